// Round 15
// baseline (180.167 us; speedup 1.0000x reference)
//
#include <hip/hip_runtime.h>
#include <stdint.h>

typedef __attribute__((ext_vector_type(8))) __bf16 bf16x8;
typedef __attribute__((ext_vector_type(4))) float f32x4;
typedef __attribute__((ext_vector_type(4))) unsigned int uint4v;

#define DI __device__ __forceinline__
#define MFMA_(a,b,c) __builtin_amdgcn_mfma_f32_16x16x32_bf16(a,b,c,0,0,0)

static constexpr int B_ = 2048;
static constexpr int T_ = 100;

DI float bf2f(unsigned short u){
  unsigned int i = ((unsigned int)u) << 16;
  float f; __builtin_memcpy(&f, &i, 4); return f;
}
DI unsigned short f2bf(float f){
  unsigned int x; __builtin_memcpy(&x, &f, 4);
  unsigned int r = (x + 0x7fffu + ((x >> 16) & 1u)) >> 16;
  return (unsigned short)r;
}
// HW packed rounding: D[15:0]=bf16(a), D[31:16]=bf16(b). RNE.
DI unsigned int pk2bf(float a, float b){
  unsigned int r;
  asm("v_cvt_pk_bf16_f32 %0, %1, %2" : "=v"(r) : "v"(a), "v"(b));
  return r;
}
DI float rcp_(float x){ return __builtin_amdgcn_rcpf(x); }
DI float sig_(float x){ return rcp_(1.0f + __expf(-x)); }
DI float tanh_(float x){ return 1.0f - 2.0f * rcp_(__expf(2.0f * x) + 1.0f); }

// Plain bf16 MFMA dot (single accumulator chain).
template<int KS>
DI f32x4 dot1(const bf16x8* a, const bf16x8* b, f32x4 acc)
{
  #pragma unroll
  for (int s = 0; s < KS; ++s)
    acc = MFMA_(a[s], b[s], acc);
  return acc;
}

// LSTM pointwise: gates i,f,g,o -> c,h; h rounded to bf16 via cvt_pk.
// (r14 lesson: do NOT fold log2e into the bf16 weights — re-quantizing at
// scaled grid points pushed absmax 9.8e-4 -> 8.9e-3. The bf16(w) grid is
// part of the validated numerics.)
DI void pw(const f32x4 (&acc)[4], float (&cc)[4], float (&hv)[4],
           unsigned short (&hH)[4])
{
  #pragma unroll
  for (int r = 0; r < 4; ++r){
    float iv = sig_(acc[0][r]);
    float fv = sig_(acc[1][r]);
    float gv = tanh_(acc[2][r]);
    float ov = sig_(acc[3][r]);
    cc[r] = fv * cc[r] + iv * gv;
    hv[r] = ov * tanh_(cc[r]);
  }
  unsigned int u01 = pk2bf(hv[0], hv[1]);
  unsigned int u23 = pk2bf(hv[2], hv[3]);
  hH[0] = (unsigned short)u01; hH[1] = (unsigned short)(u01 >> 16);
  hH[2] = (unsigned short)u23; hH[3] = (unsigned short)(u23 >> 16);
}

// ---------------------------------------------------------------------------
// Pack all weights (fp32 in) into bf16 MFMA B-fragments (UNSCALED).
// fid layout: L1(4096) L2(1536) L3(2048) L4(4096) PROJ(512) = 12288 frags.
// B-frag: lane l holds B[k = 32*s + 8*(l>>4) + e][col = 16*n + (l&15)], e=0..7.
// ---------------------------------------------------------------------------
__global__ __launch_bounds__(256) void prep_frags(
    const float* __restrict__ e1_wih, const float* __restrict__ e1_whh,
    const float* __restrict__ e2_wih, const float* __restrict__ e2_whh,
    const float* __restrict__ d1_whh,
    const float* __restrict__ d2_wih, const float* __restrict__ d2_whh,
    const float* __restrict__ w_out,
    unsigned short* __restrict__ dst)
{
  int fid = blockIdx.x * 256 + threadIdx.x;
  if (fid >= 12288) return;
  int layer, local, KS;
  if (fid < 4096)      { layer = 0; local = fid;         KS = 4; }
  else if (fid < 5632) { layer = 1; local = fid - 4096;  KS = 3; }
  else if (fid < 7680) { layer = 2; local = fid - 5632;  KS = 2; }
  else if (fid < 11776){ layer = 3; local = fid - 7680;  KS = 4; }
  else                 { layer = 4; local = fid - 11776; KS = 2; }
  int lane = local & 63;
  int ns = local >> 6;
  int s = ns % KS, n = ns / KS;
  int col = 16 * n + (lane & 15);
  int kb = 32 * s + 8 * (lane >> 4);
  union { unsigned short u[8]; uint4v v; } pk;
  #pragma unroll
  for (int e = 0; e < 8; ++e){
    int k = kb + e;
    float w = 0.0f;
    if (layer == 0){                       // e1: x(51 pad64)|h1(64); K=128, C=256
      if (k < 51) w = e1_wih[col * 51 + k];
      else if (k >= 64) w = e1_whh[col * 64 + (k - 64)];
    } else if (layer == 1){                // e2: h1(64)|h2(24 pad32); K=96, C=128
      int q = col >> 5, jj = col & 31;
      if (jj < 24){
        int r = q * 24 + jj;
        if (k < 64) w = e2_wih[r * 64 + k];
        else if (k < 88) w = e2_whh[r * 24 + (k - 64)];
      }
    } else if (layer == 2){                // d1 recurrent only; K=64, C=256
      w = d1_whh[col * 64 + k];
    } else if (layer == 3){                // d2: h3(64)|h4(64); K=128, C=256
      if (k < 64) w = d2_wih[col * 64 + k];
      else w = d2_whh[col * 64 + (k - 64)];
    } else {                               // proj: K=64, C=64 (51 used)
      if (col < 51) w = w_out[col * 64 + k];
    }
    pk.u[e] = f2bf(w);
  }
  *(uint4v*)(dst + (size_t)fid * 8) = pk.v;
}

// ---------------------------------------------------------------------------
// F1: fused encoder, ROLE-SPLIT 8 waves / 512 threads / 16 rows per block.
// waves 0-3: e1; waves 4-5: e2 (lag 1); waves 6-7: x staging.
// (r12: no enc+dec merge — register union spills at the 128-VGPR cap.
//  r13: no peel — code growth raised VGPR and cost 5us.)
// ---------------------------------------------------------------------------
__global__ __launch_bounds__(512, 1) void fused_enc(
    const float* xseq,
    const unsigned short* __restrict__ bf1u,
    const unsigned short* __restrict__ bf2u,
    const float* __restrict__ e1_bih, const float* __restrict__ e1_bhh,
    const float* __restrict__ e2_bih, const float* __restrict__ e2_bhh,
    float* __restrict__ zout)
{
  constexpr int SA1 = 136;                 // A1 row stride: x(64)|h1(64) pad
  constexpr int SB2 = 40;                  // A2 row stride: h2(24 pad32) + pad
  __shared__ __align__(16) unsigned short A1H[2][16 * SA1];
  __shared__ __align__(16) unsigned short A2B[2][16 * SB2];

  const int tid = threadIdx.x, wid = tid >> 6, lane = tid & 63;
  const int l15 = lane & 15, l4 = lane >> 4;
  const size_t s0 = (size_t)blockIdx.x * 16;
  const bool isE1 = (wid < 4);
  const bool isE2 = (wid == 4 || wid == 5);
  const bool isXW = (wid >= 6);
  const int jj1 = 16 * wid + l15;          // e1 col (wid 0-3)
  const int jj2 = 16 * (wid - 4) + l15;    // e2 col (wid 4-5)
  const int xt = tid - 384;                // 0..127 on staging waves

  const bf16x8* f1 = (const bf16x8*)bf1u;
  const bf16x8* f2 = (const bf16x8*)bf2u;
  bf16x8 b1H[16];                          // e1 frags [g*4+s]
  f32x4 init1[4];
  if (isE1){
    #pragma unroll
    for (int g = 0; g < 4; ++g){
      #pragma unroll
      for (int s = 0; s < 4; ++s)
        b1H[g * 4 + s] = f1[(size_t)(((wid + 4 * g) * 4 + s) * 64 + lane)];
      float b = e1_bih[g * 64 + jj1] + e1_bhh[g * 64 + jj1];
      init1[g] = (f32x4){b, b, b, b};
    }
  }
  bf16x8 b2H[12];                          // e2 frags [g*3+s]
  f32x4 init2[4];
  if (isE2){
    #pragma unroll
    for (int g = 0; g < 4; ++g){
      #pragma unroll
      for (int s = 0; s < 3; ++s)
        b2H[g * 3 + s] = f2[(size_t)((((wid - 4) + 2 * g) * 3 + s) * 64 + lane)];
      float b2 = (jj2 < 24) ? (e2_bih[g * 24 + jj2] + e2_bhh[g * 24 + jj2]) : 0.0f;
      init2[g] = (f32x4){b2, b2, b2, b2};
    }
  }

  for (int i = tid; i < 16 * SA1; i += 512){ A1H[0][i] = 0; A1H[1][i] = 0; }
  for (int i = tid; i < 16 * SB2; i += 512){ A2B[0][i] = 0; A2B[1][i] = 0; }
  __syncthreads();
  #pragma unroll
  for (int it = 0; it < 2; ++it){           // stage x_0 (all 512 threads)
    int idx = tid + it * 512, row = idx >> 6, k = idx & 63;
    float v = (k < 51) ? xseq[((s0 + row) * T_ + 0) * 51 + k] : 0.0f;
    A1H[0][row * SA1 + k] = f2bf(v);
  }
  __syncthreads();

  float xsA[8], xsB[8];
  if (isXW){
    #pragma unroll
    for (int it = 0; it < 8; ++it){         // prefetch x_1, x_2 (waves 6,7)
      int idx = xt + it * 128, row = idx >> 6, k = idx & 63;
      xsA[it] = (k < 51) ? xseq[((s0 + row) * T_ + 1) * 51 + k] : 0.0f;
      xsB[it] = (k < 51) ? xseq[((s0 + row) * T_ + 2) * 51 + k] : 0.0f;
    }
  }
  float cc1[4] = {0.f,0.f,0.f,0.f}, cc2[4] = {0.f,0.f,0.f,0.f};

#define ENC_STEP(TCUR, BSEL, XW)                                               \
  {                                                                            \
    const int t = (TCUR);                                                      \
    if (isE1 && t < T_){  /* e1 step t */                                      \
      bf16x8 a1H[4];                                                           \
      _Pragma("unroll")                                                        \
      for (int s = 0; s < 4; ++s)                                              \
        a1H[s] = *(const bf16x8*)&A1H[BSEL][l15 * SA1 + 32 * s + 8 * l4];      \
      f32x4 acc[4];                                                            \
      _Pragma("unroll")                                                        \
      for (int g = 0; g < 4; ++g)                                              \
        acc[g] = dot1<4>(a1H, &b1H[g * 4], init1[g]);                          \
      float hv[4]; unsigned short hH[4];                                       \
      pw(acc, cc1, hv, hH);                                                    \
      _Pragma("unroll")                                                        \
      for (int r = 0; r < 4; ++r)                                              \
        A1H[BSEL ^ 1][(4 * l4 + r) * SA1 + 64 + jj1] = hH[r];                  \
    }                                                                          \
    if (isE2 && t >= 1 && t <= T_){  /* e2 computes h2_{t-1} */                \
      bf16x8 af2[3];                                                           \
      af2[0] = *(const bf16x8*)&A1H[BSEL][l15 * SA1 + 64 + 8 * l4];            \
      af2[1] = *(const bf16x8*)&A1H[BSEL][l15 * SA1 + 96 + 8 * l4];            \
      af2[2] = *(const bf16x8*)&A2B[BSEL][l15 * SB2 + 8 * l4];                 \
      f32x4 acc[4];                                                            \
      _Pragma("unroll")                                                        \
      for (int g = 0; g < 4; ++g)                                              \
        acc[g] = dot1<3>(af2, &b2H[g * 3], init2[g]);                          \
      float hv[4]; unsigned short hH[4];                                       \
      pw(acc, cc2, hv, hH);                                                    \
      if (jj2 < 24){                                                           \
        _Pragma("unroll")                                                      \
        for (int r = 0; r < 4; ++r)                                            \
          A2B[BSEL ^ 1][(4 * l4 + r) * SB2 + jj2] = hH[r];                     \
        if (t == T_){                                                          \
          _Pragma("unroll")                                                    \
          for (int r = 0; r < 4; ++r)                                          \
            zout[(s0 + 4 * l4 + r) * 24 + jj2] = hv[r];                        \
        }                                                                      \
      }                                                                        \
    }                                                                          \
    if (isXW && t + 1 < T_){  /* x_{t+1} -> LDS; prefetch x_{t+3} */           \
      _Pragma("unroll")                                                        \
      for (int it = 0; it < 8; it += 2){                                       \
        int idx = xt + it * 128;                                               \
        int row0_ = idx >> 6, k0_ = idx & 63;                                  \
        int row1_ = (idx + 128) >> 6, k1_ = (idx + 128) & 63;                  \
        unsigned int u = pk2bf(XW[it], XW[it + 1]);                            \
        A1H[BSEL ^ 1][row0_ * SA1 + k0_] = (unsigned short)u;                  \
        A1H[BSEL ^ 1][row1_ * SA1 + k1_] = (unsigned short)(u >> 16);          \
      }                                                                        \
      if (t + 3 < T_){                                                         \
        _Pragma("unroll")                                                      \
        for (int it = 0; it < 8; ++it){                                        \
          int idx = xt + it * 128, row = idx >> 6, k = idx & 63;               \
          XW[it] = (k < 51) ? xseq[((s0 + row) * T_ + (t + 3)) * 51 + k] : 0.0f; \
        }                                                                      \
      }                                                                        \
    }                                                                          \
    asm volatile("s_waitcnt lgkmcnt(0)\n\ts_barrier" ::: "memory");            \
  }

  #pragma unroll 1
  for (int tt = 0; tt < 102; tt += 2){
    ENC_STEP(tt,     0, xsA)
    ENC_STEP(tt + 1, 1, xsB)
  }
#undef ENC_STEP
}

// ---------------------------------------------------------------------------
// F2: fused decoder, ROLE-SPLIT 8 waves / 512 threads / 16 rows per block.
// waves 0-3: d1 + proj; waves 4-7: d2. gx (d1's constant input term) is
// computed in the prologue from z in EXACT fp32 (identical math to the old
// gx_k kernel) — saves one launch with zero numerics delta.
// ---------------------------------------------------------------------------
__global__ __launch_bounds__(512, 1) void fused_dec(
    const float* __restrict__ zin,
    const float* __restrict__ d1_wih,
    const float* __restrict__ d1_bih, const float* __restrict__ d1_bhh,
    const unsigned short* __restrict__ bf3u,
    const unsigned short* __restrict__ bf4u,
    const unsigned short* __restrict__ bfpu,
    const float* __restrict__ d2_bih, const float* __restrict__ d2_bhh,
    const float* __restrict__ b_out,
    float* out)
{
  constexpr int SA4 = 136;                 // A4: h3(64)|h4(64) pad
  __shared__ __align__(16) unsigned short A4H[2][16 * SA4];

  const int tid = threadIdx.x, wid = tid >> 6, lane = tid & 63;
  const int l15 = lane & 15, l4 = lane >> 4;
  const size_t s0 = (size_t)blockIdx.x * 16;
  const bool isD1 = (wid < 4);
  const int jj3 = 16 * wid + l15;          // d1/proj col (wid 0-3)
  const int jj4 = 16 * (wid - 4) + l15;    // d2 col (wid 4-7)

  const bf16x8* f3 = (const bf16x8*)bf3u;
  const bf16x8* f4 = (const bf16x8*)bf4u;
  const bf16x8* fp = (const bf16x8*)bfpu;
  bf16x8 b3H[8], bpH[2];
  f32x4 init3[4], biasP;
  if (isD1){
    #pragma unroll
    for (int g = 0; g < 4; ++g){
      #pragma unroll
      for (int s = 0; s < 2; ++s)
        b3H[g * 2 + s] = f3[(size_t)(((wid + 4 * g) * 2 + s) * 64 + lane)];
      float b = d1_bih[g * 64 + jj3] + d1_bhh[g * 64 + jj3];
      init3[g] = (f32x4){b, b, b, b};
    }
    // gx: init3 += z · d1_W_ih^T (exact fp32, one-time prologue)
    #pragma unroll 1
    for (int k = 0; k < 24; ++k){
      float w0 = d1_wih[(jj3 +   0) * 24 + k];
      float w1 = d1_wih[(jj3 +  64) * 24 + k];
      float w2 = d1_wih[(jj3 + 128) * 24 + k];
      float w3 = d1_wih[(jj3 + 192) * 24 + k];
      #pragma unroll
      for (int r = 0; r < 4; ++r){
        float zv = zin[(s0 + 4 * l4 + r) * 24 + k];
        init3[0][r] += zv * w0; init3[1][r] += zv * w1;
        init3[2][r] += zv * w2; init3[3][r] += zv * w3;
      }
    }
    #pragma unroll
    for (int s = 0; s < 2; ++s)
      bpH[s] = fp[(size_t)((wid * 2 + s) * 64 + lane)];
    float bp = (jj3 < 51) ? b_out[jj3] : 0.0f;
    biasP = (f32x4){bp, bp, bp, bp};
  }
  bf16x8 b4H[16];
  f32x4 init4[4];
  if (!isD1){
    #pragma unroll
    for (int g = 0; g < 4; ++g){
      #pragma unroll
      for (int s = 0; s < 4; ++s)
        b4H[g * 4 + s] = f4[(size_t)((((wid - 4) + 4 * g) * 4 + s) * 64 + lane)];
      float b = d2_bih[g * 64 + jj4] + d2_bhh[g * 64 + jj4];
      init4[g] = (f32x4){b, b, b, b};
    }
  }

  for (int i = tid; i < 16 * SA4; i += 512){ A4H[0][i] = 0; A4H[1][i] = 0; }
  __syncthreads();

  float cc3[4] = {0.f,0.f,0.f,0.f}, cc4[4] = {0.f,0.f,0.f,0.f};

#define DEC_STEP(TCUR, BSEL)                                                   \
  {                                                                            \
    const int t = (TCUR);                                                      \
    bf16x8 a4[4];                                                              \
    if (isD1){                                                                 \
      a4[0] = *(const bf16x8*)&A4H[BSEL][l15 * SA4 + 8 * l4];                  \
      a4[1] = *(const bf16x8*)&A4H[BSEL][l15 * SA4 + 32 + 8 * l4];             \
      a4[2] = *(const bf16x8*)&A4H[BSEL][l15 * SA4 + 64 + 8 * l4];             \
      a4[3] = *(const bf16x8*)&A4H[BSEL][l15 * SA4 + 96 + 8 * l4];             \
    } else {                                                                   \
      _Pragma("unroll")                                                        \
      for (int s = 0; s < 4; ++s)                                              \
        a4[s] = *(const bf16x8*)&A4H[BSEL][l15 * SA4 + 32 * s + 8 * l4];       \
    }                                                                          \
    if (isD1 && t < T_){  /* d1 step t (A-frag = h3 = a4[0..1]) */             \
      f32x4 acc[4];                                                            \
      _Pragma("unroll")                                                        \
      for (int g = 0; g < 4; ++g)                                              \
        acc[g] = dot1<2>(a4, &b3H[g * 2], init3[g]);                           \
      float hv[4]; unsigned short hH[4];                                       \
      pw(acc, cc3, hv, hH);                                                    \
      _Pragma("unroll")                                                        \
      for (int r = 0; r < 4; ++r)                                              \
        A4H[BSEL ^ 1][(4 * l4 + r) * SA4 + jj3] = hH[r];                       \
    }                                                                          \
    if (!isD1 && t >= 1 && t <= T_){  /* d2 computes h4_{t-1} */               \
      f32x4 acc[4];                                                            \
      _Pragma("unroll")                                                        \
      for (int g = 0; g < 4; ++g)                                              \
        acc[g] = dot1<4>(a4, &b4H[g * 4], init4[g]);                           \
      float hv[4]; unsigned short hH[4];                                       \
      pw(acc, cc4, hv, hH);                                                    \
      _Pragma("unroll")                                                        \
      for (int r = 0; r < 4; ++r)                                              \
        A4H[BSEL ^ 1][(4 * l4 + r) * SA4 + 64 + jj4] = hH[r];                  \
    }                                                                          \
    if (isD1 && t >= 2){  /* proj of h4_{t-2} (= a4[2..3]) */                  \
      f32x4 pr = dot1<2>(&a4[2], bpH, biasP);                                  \
      if (jj3 < 51){                                                           \
        _Pragma("unroll")                                                      \
        for (int r = 0; r < 4; ++r)                                            \
          out[((s0 + 4 * l4 + r) * T_ + (t - 2)) * 51 + jj3] = pr[r];          \
      }                                                                        \
    }                                                                          \
    asm volatile("s_waitcnt lgkmcnt(0)\n\ts_barrier" ::: "memory");            \
  }

  #pragma unroll 1
  for (int tt = 0; tt < 102; tt += 2){
    DEC_STEP(tt,     0)
    DEC_STEP(tt + 1, 1)
  }
#undef DEC_STEP
}

extern "C" void kernel_launch(void* const* d_in, const int* in_sizes, int n_in,
                              void* d_out, int out_size, void* d_ws, size_t ws_size,
                              hipStream_t stream)
{
  (void)in_sizes; (void)n_in; (void)out_size; (void)ws_size;
  const float* x      = (const float*)d_in[0];
  const float* e1_wih = (const float*)d_in[1];
  const float* e1_whh = (const float*)d_in[2];
  const float* e1_bih = (const float*)d_in[3];
  const float* e1_bhh = (const float*)d_in[4];
  const float* e2_wih = (const float*)d_in[5];
  const float* e2_whh = (const float*)d_in[6];
  const float* e2_bih = (const float*)d_in[7];
  const float* e2_bhh = (const float*)d_in[8];
  const float* d1_wih = (const float*)d_in[9];
  const float* d1_whh = (const float*)d_in[10];
  const float* d1_bih = (const float*)d_in[11];
  const float* d1_bhh = (const float*)d_in[12];
  const float* d2_wih = (const float*)d_in[13];
  const float* d2_whh = (const float*)d_in[14];
  const float* d2_bih = (const float*)d_in[15];
  const float* d2_bhh = (const float*)d_in[16];
  const float* w_out  = (const float*)d_in[17];
  const float* b_out  = (const float*)d_in[18];

  char* ws = (char*)d_ws;
  unsigned short* bfrag = (unsigned short*)ws;                   // 196,608 B
  const size_t OF_L2 = 4096 * 8, OF_L3 = 5632 * 8, OF_L4 = 7680 * 8, OF_PR = 11776 * 8;
  float* zbuf = (float*)(ws + 196608);                           // 196,608 B

  prep_frags<<<48, 256, 0, stream>>>(e1_wih, e1_whh, e2_wih, e2_whh,
                                     d1_whh, d2_wih, d2_whh, w_out, bfrag);
  // F1: x -> (e1 -> e2, fused, role-split) -> z[B,24]
  fused_enc<<<128, 512, 0, stream>>>(
      x, bfrag, bfrag + OF_L2, e1_bih, e1_bhh, e2_bih, e2_bhh, zbuf);
  // F2: z -> (fp32 gx prologue + d1 -> d2 -> proj, fused, role-split) -> recon
  fused_dec<<<128, 512, 0, stream>>>(
      zbuf, d1_wih, d1_bih, d1_bhh,
      bfrag + OF_L3, bfrag + OF_L4, bfrag + OF_PR,
      d2_bih, d2_bhh, b_out, (float*)d_out);
}

// Round 16
// 172.783 us; speedup vs baseline: 1.0427x; 1.0427x over previous
//
#include <hip/hip_runtime.h>
#include <stdint.h>

typedef __attribute__((ext_vector_type(8))) __bf16 bf16x8;
typedef __attribute__((ext_vector_type(4))) float f32x4;
typedef __attribute__((ext_vector_type(4))) unsigned int uint4v;

#define DI __device__ __forceinline__
#define MFMA_(a,b,c) __builtin_amdgcn_mfma_f32_16x16x32_bf16(a,b,c,0,0,0)

static constexpr int B_ = 2048;
static constexpr int T_ = 100;

DI float bf2f(unsigned short u){
  unsigned int i = ((unsigned int)u) << 16;
  float f; __builtin_memcpy(&f, &i, 4); return f;
}
DI unsigned short f2bf(float f){
  unsigned int x; __builtin_memcpy(&x, &f, 4);
  unsigned int r = (x + 0x7fffu + ((x >> 16) & 1u)) >> 16;
  return (unsigned short)r;
}
// HW packed rounding: D[15:0]=bf16(a), D[31:16]=bf16(b). RNE.
DI unsigned int pk2bf(float a, float b){
  unsigned int r;
  asm("v_cvt_pk_bf16_f32 %0, %1, %2" : "=v"(r) : "v"(a), "v"(b));
  return r;
}
DI float rcp_(float x){ return __builtin_amdgcn_rcpf(x); }
DI float sig_(float x){ return rcp_(1.0f + __expf(-x)); }
DI float tanh_(float x){ return 1.0f - 2.0f * rcp_(__expf(2.0f * x) + 1.0f); }

// Plain bf16 MFMA dot (single accumulator chain).
template<int KS>
DI f32x4 dot1(const bf16x8* a, const bf16x8* b, f32x4 acc)
{
  #pragma unroll
  for (int s = 0; s < KS; ++s)
    acc = MFMA_(a[s], b[s], acc);
  return acc;
}

// LSTM pointwise: gates i,f,g,o -> c,h; h rounded to bf16 via cvt_pk.
DI void pw(const f32x4 (&acc)[4], float (&cc)[4], float (&hv)[4],
           unsigned short (&hH)[4])
{
  #pragma unroll
  for (int r = 0; r < 4; ++r){
    float iv = sig_(acc[0][r]);
    float fv = sig_(acc[1][r]);
    float gv = tanh_(acc[2][r]);
    float ov = sig_(acc[3][r]);
    cc[r] = fv * cc[r] + iv * gv;
    hv[r] = ov * tanh_(cc[r]);
  }
  unsigned int u01 = pk2bf(hv[0], hv[1]);
  unsigned int u23 = pk2bf(hv[2], hv[3]);
  hH[0] = (unsigned short)u01; hH[1] = (unsigned short)(u01 >> 16);
  hH[2] = (unsigned short)u23; hH[3] = (unsigned short)(u23 >> 16);
}

// ---------------------------------------------------------------------------
// Pack all weights (fp32 in) into bf16 MFMA B-fragments.
// fid layout: L1(4096) L2(1536) L3(2048) L4(4096) PROJ(512) = 12288 frags.
// B-frag: lane l holds B[k = 32*s + 8*(l>>4) + e][col = 16*n + (l&15)], e=0..7.
// ---------------------------------------------------------------------------
__global__ __launch_bounds__(256) void prep_frags(
    const float* __restrict__ e1_wih, const float* __restrict__ e1_whh,
    const float* __restrict__ e2_wih, const float* __restrict__ e2_whh,
    const float* __restrict__ d1_whh,
    const float* __restrict__ d2_wih, const float* __restrict__ d2_whh,
    const float* __restrict__ w_out,
    unsigned short* __restrict__ dst)
{
  int fid = blockIdx.x * 256 + threadIdx.x;
  if (fid >= 12288) return;
  int layer, local, KS;
  if (fid < 4096)      { layer = 0; local = fid;         KS = 4; }
  else if (fid < 5632) { layer = 1; local = fid - 4096;  KS = 3; }
  else if (fid < 7680) { layer = 2; local = fid - 5632;  KS = 2; }
  else if (fid < 11776){ layer = 3; local = fid - 7680;  KS = 4; }
  else                 { layer = 4; local = fid - 11776; KS = 2; }
  int lane = local & 63;
  int ns = local >> 6;
  int s = ns % KS, n = ns / KS;
  int col = 16 * n + (lane & 15);
  int kb = 32 * s + 8 * (lane >> 4);
  union { unsigned short u[8]; uint4v v; } pk;
  #pragma unroll
  for (int e = 0; e < 8; ++e){
    int k = kb + e;
    float w = 0.0f;
    if (layer == 0){                       // e1: x(51 pad64)|h1(64); K=128, C=256
      if (k < 51) w = e1_wih[col * 51 + k];
      else if (k >= 64) w = e1_whh[col * 64 + (k - 64)];
    } else if (layer == 1){                // e2: h1(64)|h2(24 pad32); K=96, C=128
      int q = col >> 5, jj = col & 31;
      if (jj < 24){
        int r = q * 24 + jj;
        if (k < 64) w = e2_wih[r * 64 + k];
        else if (k < 88) w = e2_whh[r * 24 + (k - 64)];
      }
    } else if (layer == 2){                // d1 recurrent only; K=64, C=256
      w = d1_whh[col * 64 + k];
    } else if (layer == 3){                // d2: h3(64)|h4(64); K=128, C=256
      if (k < 64) w = d2_wih[col * 64 + k];
      else w = d2_whh[col * 64 + (k - 64)];
    } else {                               // proj: K=64, C=64 (51 used)
      if (col < 51) w = w_out[col * 64 + k];
    }
    pk.u[e] = f2bf(w);
  }
  *(uint4v*)(dst + (size_t)fid * 8) = pk.v;
}

// Decoder-1 constant input contribution (exact fp32):
// gx[s][col] = b_ih[col] + b_hh[col] + z[s,:]·W_ih[col,:]
__global__ __launch_bounds__(256) void gx_k(
    const float* __restrict__ z, const float* __restrict__ d1_wih,
    const float* __restrict__ bih, const float* __restrict__ bhh,
    float* __restrict__ gx)
{
  int s = blockIdx.x, col = threadIdx.x;
  float acc = bih[col] + bhh[col];
  #pragma unroll
  for (int k = 0; k < 24; ++k)
    acc += z[s * 24 + k] * d1_wih[col * 24 + k];
  gx[s * 256 + col] = acc;
}

// ---------------------------------------------------------------------------
// F1: fused encoder, ROLE-SPLIT 8 waves / 512 threads / 16 rows per block.
// waves 0-3: e1 (col-tile wid, 16 MFMA + pw); waves 4-5: e2 (col-tile wid-4,
// 12 MFMA + pw, lag 1); waves 6-7: x staging. Per-role register sets are
// small (dot1) so the 2-waves/SIMD 256-unified-reg cap is satisfied
// (r7/r8's spill was dot2's ~330-reg union). Different-role waves pair on
// each SIMD -> co-issue.
// (r12: no enc+dec merge; r13: no peel; r14: no log2e weight fold;
//  r15: no gx prologue merge — each regressed. This r11 config = 172.6us.)
// ---------------------------------------------------------------------------
__global__ __launch_bounds__(512, 1) void fused_enc(
    const float* xseq,
    const unsigned short* __restrict__ bf1u,
    const unsigned short* __restrict__ bf2u,
    const float* __restrict__ e1_bih, const float* __restrict__ e1_bhh,
    const float* __restrict__ e2_bih, const float* __restrict__ e2_bhh,
    float* __restrict__ zout)
{
  constexpr int SA1 = 136;                 // A1 row stride: x(64)|h1(64) pad
  constexpr int SB2 = 40;                  // A2 row stride: h2(24 pad32) + pad
  __shared__ __align__(16) unsigned short A1H[2][16 * SA1];
  __shared__ __align__(16) unsigned short A2B[2][16 * SB2];

  const int tid = threadIdx.x, wid = tid >> 6, lane = tid & 63;
  const int l15 = lane & 15, l4 = lane >> 4;
  const size_t s0 = (size_t)blockIdx.x * 16;
  const bool isE1 = (wid < 4);
  const bool isE2 = (wid == 4 || wid == 5);
  const bool isXW = (wid >= 6);
  const int jj1 = 16 * wid + l15;          // e1 col (wid 0-3)
  const int jj2 = 16 * (wid - 4) + l15;    // e2 col (wid 4-5)
  const int xt = tid - 384;                // 0..127 on staging waves

  const bf16x8* f1 = (const bf16x8*)bf1u;
  const bf16x8* f2 = (const bf16x8*)bf2u;
  bf16x8 b1H[16];                          // e1 frags [g*4+s]
  f32x4 init1[4];
  if (isE1){
    #pragma unroll
    for (int g = 0; g < 4; ++g){
      #pragma unroll
      for (int s = 0; s < 4; ++s)
        b1H[g * 4 + s] = f1[(size_t)(((wid + 4 * g) * 4 + s) * 64 + lane)];
      float b = e1_bih[g * 64 + jj1] + e1_bhh[g * 64 + jj1];
      init1[g] = (f32x4){b, b, b, b};
    }
  }
  bf16x8 b2H[12];                          // e2 frags [g*3+s]
  f32x4 init2[4];
  if (isE2){
    #pragma unroll
    for (int g = 0; g < 4; ++g){
      #pragma unroll
      for (int s = 0; s < 3; ++s)
        b2H[g * 3 + s] = f2[(size_t)((((wid - 4) + 2 * g) * 3 + s) * 64 + lane)];
      float b2 = (jj2 < 24) ? (e2_bih[g * 24 + jj2] + e2_bhh[g * 24 + jj2]) : 0.0f;
      init2[g] = (f32x4){b2, b2, b2, b2};
    }
  }

  for (int i = tid; i < 16 * SA1; i += 512){ A1H[0][i] = 0; A1H[1][i] = 0; }
  for (int i = tid; i < 16 * SB2; i += 512){ A2B[0][i] = 0; A2B[1][i] = 0; }
  __syncthreads();
  #pragma unroll
  for (int it = 0; it < 2; ++it){           // stage x_0 (all 512 threads)
    int idx = tid + it * 512, row = idx >> 6, k = idx & 63;
    float v = (k < 51) ? xseq[((s0 + row) * T_ + 0) * 51 + k] : 0.0f;
    A1H[0][row * SA1 + k] = f2bf(v);
  }
  __syncthreads();

  float xsA[8], xsB[8];
  if (isXW){
    #pragma unroll
    for (int it = 0; it < 8; ++it){         // prefetch x_1, x_2 (waves 6,7)
      int idx = xt + it * 128, row = idx >> 6, k = idx & 63;
      xsA[it] = (k < 51) ? xseq[((s0 + row) * T_ + 1) * 51 + k] : 0.0f;
      xsB[it] = (k < 51) ? xseq[((s0 + row) * T_ + 2) * 51 + k] : 0.0f;
    }
  }
  float cc1[4] = {0.f,0.f,0.f,0.f}, cc2[4] = {0.f,0.f,0.f,0.f};

#define ENC_STEP(TCUR, BSEL, XW)                                               \
  {                                                                            \
    const int t = (TCUR);                                                      \
    if (isE1 && t < T_){  /* e1 step t */                                      \
      bf16x8 a1H[4];                                                           \
      _Pragma("unroll")                                                        \
      for (int s = 0; s < 4; ++s)                                              \
        a1H[s] = *(const bf16x8*)&A1H[BSEL][l15 * SA1 + 32 * s + 8 * l4];      \
      f32x4 acc[4];                                                            \
      _Pragma("unroll")                                                        \
      for (int g = 0; g < 4; ++g)                                              \
        acc[g] = dot1<4>(a1H, &b1H[g * 4], init1[g]);                          \
      float hv[4]; unsigned short hH[4];                                       \
      pw(acc, cc1, hv, hH);                                                    \
      _Pragma("unroll")                                                        \
      for (int r = 0; r < 4; ++r)                                              \
        A1H[BSEL ^ 1][(4 * l4 + r) * SA1 + 64 + jj1] = hH[r];                  \
    }                                                                          \
    if (isE2 && t >= 1 && t <= T_){  /* e2 computes h2_{t-1} */                \
      bf16x8 af2[3];                                                           \
      af2[0] = *(const bf16x8*)&A1H[BSEL][l15 * SA1 + 64 + 8 * l4];            \
      af2[1] = *(const bf16x8*)&A1H[BSEL][l15 * SA1 + 96 + 8 * l4];            \
      af2[2] = *(const bf16x8*)&A2B[BSEL][l15 * SB2 + 8 * l4];                 \
      f32x4 acc[4];                                                            \
      _Pragma("unroll")                                                        \
      for (int g = 0; g < 4; ++g)                                              \
        acc[g] = dot1<3>(af2, &b2H[g * 3], init2[g]);                          \
      float hv[4]; unsigned short hH[4];                                       \
      pw(acc, cc2, hv, hH);                                                    \
      if (jj2 < 24){                                                           \
        _Pragma("unroll")                                                      \
        for (int r = 0; r < 4; ++r)                                            \
          A2B[BSEL ^ 1][(4 * l4 + r) * SB2 + jj2] = hH[r];                     \
        if (t == T_){                                                          \
          _Pragma("unroll")                                                    \
          for (int r = 0; r < 4; ++r)                                          \
            zout[(s0 + 4 * l4 + r) * 24 + jj2] = hv[r];                        \
        }                                                                      \
      }                                                                        \
    }                                                                          \
    if (isXW && t + 1 < T_){  /* x_{t+1} -> LDS; prefetch x_{t+3} */           \
      _Pragma("unroll")                                                        \
      for (int it = 0; it < 8; it += 2){                                       \
        int idx = xt + it * 128;                                               \
        int row0_ = idx >> 6, k0_ = idx & 63;                                  \
        int row1_ = (idx + 128) >> 6, k1_ = (idx + 128) & 63;                  \
        unsigned int u = pk2bf(XW[it], XW[it + 1]);                            \
        A1H[BSEL ^ 1][row0_ * SA1 + k0_] = (unsigned short)u;                  \
        A1H[BSEL ^ 1][row1_ * SA1 + k1_] = (unsigned short)(u >> 16);          \
      }                                                                        \
      if (t + 3 < T_){                                                         \
        _Pragma("unroll")                                                      \
        for (int it = 0; it < 8; ++it){                                        \
          int idx = xt + it * 128, row = idx >> 6, k = idx & 63;               \
          XW[it] = (k < 51) ? xseq[((s0 + row) * T_ + (t + 3)) * 51 + k] : 0.0f; \
        }                                                                      \
      }                                                                        \
    }                                                                          \
    asm volatile("s_waitcnt lgkmcnt(0)\n\ts_barrier" ::: "memory");            \
  }

  #pragma unroll 1
  for (int tt = 0; tt < 102; tt += 2){
    ENC_STEP(tt,     0, xsA)
    ENC_STEP(tt + 1, 1, xsB)
  }
#undef ENC_STEP
}

// ---------------------------------------------------------------------------
// F2: fused decoder, ROLE-SPLIT 8 waves / 512 threads / 16 rows per block.
// waves 0-3: d1 (8 MFMA + pw) + proj (8 MFMA + stores); waves 4-7: d2
// (16 MFMA + pw). Within a step d1/d2/proj are independent (lag structure);
// all share the single A4 [h3|h4] double-buffered state tile.
// ---------------------------------------------------------------------------
__global__ __launch_bounds__(512, 1) void fused_dec(
    const float* __restrict__ gxin,
    const unsigned short* __restrict__ bf3u,
    const unsigned short* __restrict__ bf4u,
    const unsigned short* __restrict__ bfpu,
    const float* __restrict__ d2_bih, const float* __restrict__ d2_bhh,
    const float* __restrict__ b_out,
    float* out)
{
  constexpr int SA4 = 136;                 // A4: h3(64)|h4(64) pad
  __shared__ __align__(16) unsigned short A4H[2][16 * SA4];

  const int tid = threadIdx.x, wid = tid >> 6, lane = tid & 63;
  const int l15 = lane & 15, l4 = lane >> 4;
  const size_t s0 = (size_t)blockIdx.x * 16;
  const bool isD1 = (wid < 4);
  const int jj3 = 16 * wid + l15;          // d1/proj col (wid 0-3)
  const int jj4 = 16 * (wid - 4) + l15;    // d2 col (wid 4-7)

  const bf16x8* f3 = (const bf16x8*)bf3u;
  const bf16x8* f4 = (const bf16x8*)bf4u;
  const bf16x8* fp = (const bf16x8*)bfpu;
  bf16x8 b3H[8], bpH[2];
  f32x4 init3[4], biasP;
  if (isD1){
    #pragma unroll
    for (int g = 0; g < 4; ++g){
      #pragma unroll
      for (int s = 0; s < 2; ++s)
        b3H[g * 2 + s] = f3[(size_t)(((wid + 4 * g) * 2 + s) * 64 + lane)];
      #pragma unroll
      for (int r = 0; r < 4; ++r)
        init3[g][r] = gxin[(s0 + 4 * l4 + r) * 256 + jj3 + 64 * g];
    }
    #pragma unroll
    for (int s = 0; s < 2; ++s)
      bpH[s] = fp[(size_t)((wid * 2 + s) * 64 + lane)];
    float bp = (jj3 < 51) ? b_out[jj3] : 0.0f;
    biasP = (f32x4){bp, bp, bp, bp};
  }
  bf16x8 b4H[16];
  f32x4 init4[4];
  if (!isD1){
    #pragma unroll
    for (int g = 0; g < 4; ++g){
      #pragma unroll
      for (int s = 0; s < 4; ++s)
        b4H[g * 4 + s] = f4[(size_t)((((wid - 4) + 4 * g) * 4 + s) * 64 + lane)];
      float b = d2_bih[g * 64 + jj4] + d2_bhh[g * 64 + jj4];
      init4[g] = (f32x4){b, b, b, b};
    }
  }

  for (int i = tid; i < 16 * SA4; i += 512){ A4H[0][i] = 0; A4H[1][i] = 0; }
  __syncthreads();

  float cc3[4] = {0.f,0.f,0.f,0.f}, cc4[4] = {0.f,0.f,0.f,0.f};

#define DEC_STEP(TCUR, BSEL)                                                   \
  {                                                                            \
    const int t = (TCUR);                                                      \
    bf16x8 a4[4];                                                              \
    if (isD1){                                                                 \
      a4[0] = *(const bf16x8*)&A4H[BSEL][l15 * SA4 + 8 * l4];                  \
      a4[1] = *(const bf16x8*)&A4H[BSEL][l15 * SA4 + 32 + 8 * l4];             \
      a4[2] = *(const bf16x8*)&A4H[BSEL][l15 * SA4 + 64 + 8 * l4];             \
      a4[3] = *(const bf16x8*)&A4H[BSEL][l15 * SA4 + 96 + 8 * l4];             \
    } else {                                                                   \
      _Pragma("unroll")                                                        \
      for (int s = 0; s < 4; ++s)                                              \
        a4[s] = *(const bf16x8*)&A4H[BSEL][l15 * SA4 + 32 * s + 8 * l4];       \
    }                                                                          \
    if (isD1 && t < T_){  /* d1 step t (A-frag = h3 = a4[0..1]) */             \
      f32x4 acc[4];                                                            \
      _Pragma("unroll")                                                        \
      for (int g = 0; g < 4; ++g)                                              \
        acc[g] = dot1<2>(a4, &b3H[g * 2], init3[g]);                           \
      float hv[4]; unsigned short hH[4];                                       \
      pw(acc, cc3, hv, hH);                                                    \
      _Pragma("unroll")                                                        \
      for (int r = 0; r < 4; ++r)                                              \
        A4H[BSEL ^ 1][(4 * l4 + r) * SA4 + jj3] = hH[r];                       \
    }                                                                          \
    if (!isD1 && t >= 1 && t <= T_){  /* d2 computes h4_{t-1} */               \
      f32x4 acc[4];                                                            \
      _Pragma("unroll")                                                        \
      for (int g = 0; g < 4; ++g)                                              \
        acc[g] = dot1<4>(a4, &b4H[g * 4], init4[g]);                           \
      float hv[4]; unsigned short hH[4];                                       \
      pw(acc, cc4, hv, hH);                                                    \
      _Pragma("unroll")                                                        \
      for (int r = 0; r < 4; ++r)                                              \
        A4H[BSEL ^ 1][(4 * l4 + r) * SA4 + 64 + jj4] = hH[r];                  \
    }                                                                          \
    if (isD1 && t >= 2){  /* proj of h4_{t-2} (= a4[2..3]) */                  \
      f32x4 pr = dot1<2>(&a4[2], bpH, biasP);                                  \
      if (jj3 < 51){                                                           \
        _Pragma("unroll")                                                      \
        for (int r = 0; r < 4; ++r)                                            \
          out[((s0 + 4 * l4 + r) * T_ + (t - 2)) * 51 + jj3] = pr[r];          \
      }                                                                        \
    }                                                                          \
    asm volatile("s_waitcnt lgkmcnt(0)\n\ts_barrier" ::: "memory");            \
  }

  #pragma unroll 1
  for (int tt = 0; tt < 102; tt += 2){
    DEC_STEP(tt,     0)
    DEC_STEP(tt + 1, 1)
  }
#undef DEC_STEP
}

extern "C" void kernel_launch(void* const* d_in, const int* in_sizes, int n_in,
                              void* d_out, int out_size, void* d_ws, size_t ws_size,
                              hipStream_t stream)
{
  (void)in_sizes; (void)n_in; (void)out_size; (void)ws_size;
  const float* x      = (const float*)d_in[0];
  const float* e1_wih = (const float*)d_in[1];
  const float* e1_whh = (const float*)d_in[2];
  const float* e1_bih = (const float*)d_in[3];
  const float* e1_bhh = (const float*)d_in[4];
  const float* e2_wih = (const float*)d_in[5];
  const float* e2_whh = (const float*)d_in[6];
  const float* e2_bih = (const float*)d_in[7];
  const float* e2_bhh = (const float*)d_in[8];
  const float* d1_wih = (const float*)d_in[9];
  const float* d1_whh = (const float*)d_in[10];
  const float* d1_bih = (const float*)d_in[11];
  const float* d1_bhh = (const float*)d_in[12];
  const float* d2_wih = (const float*)d_in[13];
  const float* d2_whh = (const float*)d_in[14];
  const float* d2_bih = (const float*)d_in[15];
  const float* d2_bhh = (const float*)d_in[16];
  const float* w_out  = (const float*)d_in[17];
  const float* b_out  = (const float*)d_in[18];

  char* ws = (char*)d_ws;
  unsigned short* bfrag = (unsigned short*)ws;                   // 196,608 B
  const size_t OF_L2 = 4096 * 8, OF_L3 = 5632 * 8, OF_L4 = 7680 * 8, OF_PR = 11776 * 8;
  float* zbuf  = (float*)(ws + 196608);                          // 196,608 B
  float* gxbuf = (float*)(ws + 196608 + 196608);                 // 2,097,152 B

  prep_frags<<<48, 256, 0, stream>>>(e1_wih, e1_whh, e2_wih, e2_whh,
                                     d1_whh, d2_wih, d2_whh, w_out, bfrag);
  // F1: x -> (e1 -> e2, fused, role-split) -> z[B,24]
  fused_enc<<<128, 512, 0, stream>>>(
      x, bfrag, bfrag + OF_L2, e1_bih, e1_bhh, e2_bih, e2_bhh, zbuf);
  // decoder-1 constant input contribution (exact fp32)
  gx_k<<<2048, 256, 0, stream>>>(zbuf, d1_wih, d1_bih, d1_bhh, gxbuf);
  // F2: gx -> (d1 -> d2 -> proj, fused, role-split) -> recon[B,T,51] fp32
  fused_dec<<<128, 512, 0, stream>>>(
      gxbuf, bfrag + OF_L3, bfrag + OF_L4, bfrag + OF_PR,
      d2_bih, d2_bhh, b_out, (float*)d_out);
}